// Round 1
// 3227.576 us; speedup vs baseline: 1.0996x; 1.0996x over previous
//
#include <hip/hip_runtime.h>
#include <hip/hip_bf16.h>
#include <math.h>

typedef __bf16 bf16;
typedef __attribute__((ext_vector_type(8))) __bf16 bf16x8;
typedef __attribute__((ext_vector_type(4))) __bf16 bf16x4;
typedef __attribute__((ext_vector_type(4))) float f32x4;

// ---------------- constants ----------------
constexpr int cB = 16, cC = 3, cH = 64, cW = 672;
constexpr int cP = 16, cE = 768, cHEADS = 12, cL = 12;
constexpr int cMLP = 3072, cOUT = 2048;
constexpr int cPH = 4, cPW = 42, cNPAT = 168, cSEQ = 169;
constexpr int cN = cB * cSEQ;          // 2704 packed rows
constexpr int cMp = 2816;              // padded to 22*128
constexpr int cDH = 64;
constexpr int NJT = 4, JT = 43;        // 4 key tiles of 43 (last = 40)

enum { EPI_F32 = 0, EPI_RES = 1, EPI_GELU_BF16 = 2, EPI_BF16 = 3 };

// ---------------- async global->LDS 16B per lane ----------------
// LDS side is wave-uniform base + lane*16 (HW-added); global side is per-lane gather.
__device__ __forceinline__ void async16(const bf16* g, bf16* l) {
    __builtin_amdgcn_global_load_lds(
        (__attribute__((address_space(1))) void*)(void*)g,
        (__attribute__((address_space(3))) void*)(void*)l,
        16, 0, 0);
}

// bijective XCD-chunk swizzle (m204): consecutive HW block ids round-robin XCDs;
// remap so each XCD owns a contiguous chunk of the linear grid -> A-panel L2 reuse.
__device__ __forceinline__ int xcd_swz(int orig, int nwg) {
    int q = nwg >> 3, r = nwg & 7;
    int xcd = orig & 7, idx = orig >> 3;
    return (xcd < r ? xcd * (q + 1) : r * (q + 1) + (xcd - r) * q) + idx;
}

// ---------------- patchify: pixels -> bf16 patch matrix [2688, 768] ----------------
__global__ __launch_bounds__(256) void patchify_kernel(
    const float* __restrict__ px, bf16* __restrict__ Ap)
{
    int idx = blockIdx.x * 256 + threadIdx.x;            // over 2688*768
    if (idx >= cB * cNPAT * cE) return;
    int gp = idx / cE, e = idx - gp * cE;
    int b = gp / cNPAT, p = gp - b * cNPAT;
    int ph = p / cPW, pw = p - ph * cPW;
    int c = e >> 8, r = (e >> 4) & 15, col = e & 15;
    float v = px[(((size_t)b * cC + c) * cH + (ph * cP + r)) * cW + pw * cP + col];
    Ap[idx] = (bf16)v;
}

// ---------------- assemble: cls + pe + pos -> x fp32 [2704, 768] ----------------
__global__ __launch_bounds__(256) void assemble_kernel(
    const float* __restrict__ pe, const float* __restrict__ row_emb,
    const float* __restrict__ col_emb, const float* __restrict__ cls,
    float* __restrict__ x)
{
    int idx = blockIdx.x * 256 + threadIdx.x;            // over 2704*768
    if (idx >= cN * cE) return;
    int row = idx / cE, e = idx - row * cE;
    int b = row / cSEQ, s = row - b * cSEQ;
    float v;
    if (s == 0) {
        v = cls[e];
    } else {
        int p = s - 1, ph = p / cPW, pw = p - ph * cPW;
        float pos = (e < 384) ? row_emb[ph * 384 + e] : col_emb[pw * 384 + e - 384];
        v = pe[((size_t)b * cNPAT + p) * cE + e] + pos;
    }
    x[idx] = v;
}

// ---------------- fp32 -> bf16 convert (x4 vectorized) ----------------
__global__ __launch_bounds__(256) void f2b_kernel(
    const float* __restrict__ in, bf16* __restrict__ out, int n4)
{
    int i = blockIdx.x * 256 + threadIdx.x;
    if (i >= n4) return;
    f32x4 v = ((const f32x4*)in)[i];
    bf16x4 r;
    r[0] = (bf16)v[0]; r[1] = (bf16)v[1]; r[2] = (bf16)v[2]; r[3] = (bf16)v[3];
    ((bf16x4*)out)[i] = r;
}

// ---------------- batched layer-weight conversion: 4 segments -> wbuf ----------------
// seg sizes (f32x4 units): in_w 442368, out_w 147456, mlp_w1 589824, mlp_w2 589824
__global__ __launch_bounds__(256) void conv4_kernel(
    const float* __restrict__ s0, const float* __restrict__ s1,
    const float* __restrict__ s2, const float* __restrict__ s3,
    bf16* __restrict__ dst)
{
    int i = blockIdx.x * 256 + threadIdx.x;
    if (i >= 1769472) return;
    const float* src; size_t off;
    if (i < 442368)       { src = s0 + (size_t)i * 4;             off = (size_t)i * 4; }
    else if (i < 589824)  { int j = i - 442368;  src = s1 + (size_t)j * 4; off = 1769472 + (size_t)j * 4; }
    else if (i < 1179648) { int j = i - 589824;  src = s2 + (size_t)j * 4; off = 2359296 + (size_t)j * 4; }
    else                  { int j = i - 1179648; src = s3 + (size_t)j * 4; off = 4718592 + (size_t)j * 4; }
    f32x4 v = *(const f32x4*)src;
    bf16x4 r;
    r[0] = (bf16)v[0]; r[1] = (bf16)v[1]; r[2] = (bf16)v[2]; r[3] = (bf16)v[3];
    *(bf16x4*)(dst + off) = r;
}

// ---------------- layernorm over D cols; out bf16 or fp32 ----------------
__global__ __launch_bounds__(256) void ln_kernel(
    const float* __restrict__ x, const float* __restrict__ g,
    const float* __restrict__ bta, bf16* __restrict__ outB,
    float* __restrict__ outF, int D)
{
    const int row = blockIdx.x;
    const float* xr = x + (size_t)row * D;
    float s = 0.f, s2 = 0.f;
    for (int d = threadIdx.x; d < D; d += 256) { float v = xr[d]; s += v; s2 += v * v; }
    #pragma unroll
    for (int off = 32; off > 0; off >>= 1) {
        s  += __shfl_down(s, off);
        s2 += __shfl_down(s2, off);
    }
    __shared__ float rs[4], rs2[4];
    if ((threadIdx.x & 63) == 0) { rs[threadIdx.x >> 6] = s; rs2[threadIdx.x >> 6] = s2; }
    __syncthreads();
    s = rs[0] + rs[1] + rs[2] + rs[3];
    s2 = rs2[0] + rs2[1] + rs2[2] + rs2[3];
    const float mean = s / D;
    const float rstd = rsqrtf(s2 / D - mean * mean + 1e-5f);
    for (int d = threadIdx.x; d < D; d += 256) {
        float v = (xr[d] - mean) * rstd * g[d] + bta[d];
        if (outB) outB[(size_t)row * D + d] = (bf16)v;
        else      outF[(size_t)row * D + d] = v;
    }
}

// ---------------- bf16 MFMA GEMM: out = epi(A[M,K] @ W[N,K]^T + bias) ----------------
// 128x128 tile, BK=64, DOUBLE-buffered LDS (64 KB), global_load_lds width=16.
// Prefetch for tile k+1 issued right after the barrier -> the vmcnt(0) drain at the
// NEXT barrier covers a DMA that had the whole 32-MFMA compute phase in flight.
// LDS layout XOR-swizzled: row r, physical 16B-chunk c holds global chunk c^(r&7)
// -> quad ds_read_b128 is bank-balanced (2 lanes per 4-bank group = free).
__global__ __launch_bounds__(256, 2) void gemm_bt_kernel(
    const bf16* __restrict__ A, const bf16* __restrict__ Bw,
    const float* __restrict__ bias, const float* __restrict__ res,
    float* __restrict__ outF, bf16* __restrict__ outB,
    int M, int N, int K, int epi)
{
    __shared__ bf16 sA[2 * 128 * 64];    // 32 KB
    __shared__ bf16 sB[2 * 128 * 64];    // 32 KB

    const int tid  = threadIdx.x;
    const int lane = tid & 63;
    const int wave = tid >> 6;

    const int nwg  = gridDim.x * gridDim.y;
    const int swz  = xcd_swz(blockIdx.y * gridDim.x + blockIdx.x, nwg);
    const int bm = (swz / gridDim.x) * 128;
    const int bn = (swz % gridDim.x) * 128;
    const int wm = (wave & 1) * 64;
    const int wn = (wave >> 1) * 64;

    // staging geometry: wave covers rows [wave*32, wave*32+32), 4 DMAs of 8 rows each.
    // lane l -> local row l>>3, global 16B-chunk (l&7)^(l>>3)  (since row&7 == l>>3)
    const int r_in = lane >> 3;                    // 0..7
    const int swz_col = ((lane & 7) ^ r_in) * 8;   // global elem offset of this lane's chunk

    const int m_lo = lane & 15;
    const int quad = lane >> 4;

    f32x4 acc[4][4];
    #pragma unroll
    for (int i = 0; i < 4; ++i)
        #pragma unroll
        for (int j = 0; j < 4; ++j) {
            f32x4 z = {0.f, 0.f, 0.f, 0.f};
            acc[i][j] = z;
        }

    const int nk = K >> 6;

    auto stage = [&](int kt, int buf) {
        const int k0 = kt << 6;
        const bf16* gA = A  + (size_t)(bm + wave * 32 + r_in) * K + k0 + swz_col;
        const bf16* gB = Bw + (size_t)(bn + wave * 32 + r_in) * K + k0 + swz_col;
        bf16* lA = sA + buf * 8192 + (wave * 32) * 64;
        bf16* lB = sB + buf * 8192 + (wave * 32) * 64;
        #pragma unroll
        for (int d = 0; d < 4; ++d) {
            async16(gA + (size_t)(d * 8) * K, lA + d * 512);
            async16(gB + (size_t)(d * 8) * K, lB + d * 512);
        }
    };

    stage(0, 0);

    for (int kt = 0; kt < nk; ++kt) {
        __syncthreads();                 // drains vmcnt(0): tile kt complete; all waves done reading other buf
        if (kt + 1 < nk) stage(kt + 1, (kt + 1) & 1);

        const bf16* bufA = sA + (kt & 1) * 8192;
        const bf16* bufB = sB + (kt & 1) * 8192;

        bf16x8 af[2][4], bfr[2][4];
        #pragma unroll
        for (int j = 0; j < 2; ++j)
            #pragma unroll
            for (int i = 0; i < 4; ++i) {
                const int c = ((quad + j * 4) ^ (m_lo & 7)) * 8;   // swizzled chunk
                af[j][i]  = *(const bf16x8*)(bufA + (wm + i * 16 + m_lo) * 64 + c);
                bfr[j][i] = *(const bf16x8*)(bufB + (wn + i * 16 + m_lo) * 64 + c);
            }
        #pragma unroll
        for (int j = 0; j < 2; ++j)
            #pragma unroll
            for (int mi = 0; mi < 4; ++mi)
                #pragma unroll
                for (int ni = 0; ni < 4; ++ni)
                    acc[mi][ni] = __builtin_amdgcn_mfma_f32_16x16x32_bf16(
                        af[j][mi], bfr[j][ni], acc[mi][ni], 0, 0, 0);
    }

    // epilogue: C/D layout col=lane&15, row=quad*4+r  (verified m89/m91)
    #pragma unroll
    for (int mi = 0; mi < 4; ++mi) {
        #pragma unroll
        for (int ni = 0; ni < 4; ++ni) {
            #pragma unroll
            for (int r = 0; r < 4; ++r) {
                int row = bm + wm + mi * 16 + quad * 4 + r;
                int col = bn + wn + ni * 16 + m_lo;
                float v = acc[mi][ni][r] + bias[col];
                if (epi == EPI_RES) {
                    v += res[(size_t)row * N + col];
                    outF[(size_t)row * N + col] = v;
                } else if (epi == EPI_GELU_BF16) {
                    v = v * 0.5f * (1.0f + erff(v * 0.70710678118f));
                    outB[(size_t)row * N + col] = (bf16)v;
                } else if (epi == EPI_BF16) {
                    outB[(size_t)row * N + col] = (bf16)v;
                } else {
                    outF[(size_t)row * N + col] = v;
                }
            }
        }
    }
}

// ---------------- narrow-N variant: BM=128, BN=64, 3 blocks/CU ----------------
// For N=768 GEMMs the 128x128 grid is only 132 blocks (half the CUs idle, 1 wave/SIMD
// on the rest -> latency-bound, MfmaUtil 6.6%). BN=64 doubles the grid (264 blocks)
// and cuts LDS to 48 KB -> 3 blocks/CU = 3 waves/SIMD of latency hiding.
__global__ __launch_bounds__(256, 3) void gemm_bt64_kernel(
    const bf16* __restrict__ A, const bf16* __restrict__ Bw,
    const float* __restrict__ bias, const float* __restrict__ res,
    float* __restrict__ outF, bf16* __restrict__ outB,
    int M, int N, int K, int epi)
{
    __shared__ bf16 sA[2 * 128 * 64];    // 32 KB
    __shared__ bf16 sB[2 * 64 * 64];     // 16 KB

    const int tid  = threadIdx.x;
    const int lane = tid & 63;
    const int wave = tid >> 6;

    const int nwg  = gridDim.x * gridDim.y;
    const int swz  = xcd_swz(blockIdx.y * gridDim.x + blockIdx.x, nwg);
    const int bm = (swz / gridDim.x) * 128;
    const int bn = (swz % gridDim.x) * 64;
    const int wm = (wave & 1) * 64;      // 2x2 wave grid, wave tile 64x32
    const int wn = (wave >> 1) * 32;

    const int r_in = lane >> 3;                    // 0..7
    const int swz_col = ((lane & 7) ^ r_in) * 8;
    const int m_lo = lane & 15;
    const int quad = lane >> 4;

    f32x4 acc[4][2];
    #pragma unroll
    for (int i = 0; i < 4; ++i)
        #pragma unroll
        for (int j = 0; j < 2; ++j) {
            f32x4 z = {0.f, 0.f, 0.f, 0.f};
            acc[i][j] = z;
        }

    const int nk = K >> 6;

    auto stage = [&](int kt, int buf) {
        const int k0 = kt << 6;
        // A: wave covers rows [wave*32, wave*32+32): 4 DMAs of 8 rows
        const bf16* gA = A  + (size_t)(bm + wave * 32 + r_in) * K + k0 + swz_col;
        bf16* lA = sA + buf * 8192 + (wave * 32) * 64;
        #pragma unroll
        for (int d = 0; d < 4; ++d)
            async16(gA + (size_t)(d * 8) * K, lA + d * 512);
        // B: wave covers rows [wave*16, wave*16+16): 2 DMAs of 8 rows
        const bf16* gB = Bw + (size_t)(bn + wave * 16 + r_in) * K + k0 + swz_col;
        bf16* lB = sB + buf * 4096 + (wave * 16) * 64;
        #pragma unroll
        for (int d = 0; d < 2; ++d)
            async16(gB + (size_t)(d * 8) * K, lB + d * 512);
    };

    stage(0, 0);

    for (int kt = 0; kt < nk; ++kt) {
        __syncthreads();
        if (kt + 1 < nk) stage(kt + 1, (kt + 1) & 1);

        const bf16* bufA = sA + (kt & 1) * 8192;
        const bf16* bufB = sB + (kt & 1) * 4096;

        bf16x8 af[2][4], bfr[2][2];
        #pragma unroll
        for (int j = 0; j < 2; ++j) {
            #pragma unroll
            for (int i = 0; i < 4; ++i) {
                const int c = ((quad + j * 4) ^ (m_lo & 7)) * 8;
                af[j][i] = *(const bf16x8*)(bufA + (wm + i * 16 + m_lo) * 64 + c);
            }
            #pragma unroll
            for (int i = 0; i < 2; ++i) {
                const int c = ((quad + j * 4) ^ (m_lo & 7)) * 8;
                bfr[j][i] = *(const bf16x8*)(bufB + (wn + i * 16 + m_lo) * 64 + c);
            }
        }
        #pragma unroll
        for (int j = 0; j < 2; ++j)
            #pragma unroll
            for (int mi = 0; mi < 4; ++mi)
                #pragma unroll
                for (int ni = 0; ni < 2; ++ni)
                    acc[mi][ni] = __builtin_amdgcn_mfma_f32_16x16x32_bf16(
                        af[j][mi], bfr[j][ni], acc[mi][ni], 0, 0, 0);
    }

    #pragma unroll
    for (int mi = 0; mi < 4; ++mi) {
        #pragma unroll
        for (int ni = 0; ni < 2; ++ni) {
            #pragma unroll
            for (int r = 0; r < 4; ++r) {
                int row = bm + wm + mi * 16 + quad * 4 + r;
                int col = bn + wn + ni * 16 + m_lo;
                float v = acc[mi][ni][r] + bias[col];
                if (epi == EPI_RES) {
                    v += res[(size_t)row * N + col];
                    outF[(size_t)row * N + col] = v;
                } else if (epi == EPI_GELU_BF16) {
                    v = v * 0.5f * (1.0f + erff(v * 0.70710678118f));
                    outB[(size_t)row * N + col] = (bf16)v;
                } else if (epi == EPI_BF16) {
                    outB[(size_t)row * N + col] = (bf16)v;
                } else {
                    outF[(size_t)row * N + col] = v;
                }
            }
        }
    }
}

// ---------------- attention part 1: block per (head, image, key-tile) ----------------
// qkv is bf16 [2816, 2304]; online softmax over <=43 keys; partial (m,l,o[64]) out.
__global__ __launch_bounds__(192) void attn_part_kernel(
    const bf16* __restrict__ qkv, bf16* __restrict__ op, float* __restrict__ ml)
{
    __shared__ float sK[JT * cDH];       // 11,008 B
    __shared__ bf16  sV[JT * cDH];       //  5,504 B
    const int h = blockIdx.x, b = blockIdx.y, jt = blockIdx.z;
    const int tid = threadIdx.x;
    const int j0 = jt * JT;
    const int cnt = min(JT, cSEQ - j0);
    const size_t base = (size_t)b * cSEQ * (3 * cE) + (size_t)h * cDH;

    for (int idx = tid; idx < cnt * cDH; idx += 192) {
        int j = idx >> 6, d = idx & 63;
        const bf16* p = qkv + base + (size_t)(j0 + j) * (3 * cE) + d;
        sK[idx] = (float)p[cE];
        sV[idx] = p[2 * cE];
    }
    __syncthreads();
    if (tid >= cSEQ) return;

    const bf16x8* q8 = (const bf16x8*)(qkv + base + (size_t)tid * (3 * cE));
    float q[cDH];
    #pragma unroll
    for (int c = 0; c < 8; ++c) {
        bf16x8 t = q8[c];
        #pragma unroll
        for (int u = 0; u < 8; ++u) q[c * 8 + u] = (float)t[u] * 0.125f;  // 1/sqrt(64)
    }

    float m = -1e30f, l = 0.f;
    float o[cDH];
    #pragma unroll
    for (int d = 0; d < cDH; ++d) o[d] = 0.f;

    for (int j = 0; j < cnt; ++j) {
        const f32x4* kr = (const f32x4*)(sK + j * cDH);
        float s = 0.f;
        #pragma unroll
        for (int c = 0; c < 16; ++c) {
            f32x4 kv = kr[c];
            s += q[c*4+0]*kv[0] + q[c*4+1]*kv[1] + q[c*4+2]*kv[2] + q[c*4+3]*kv[3];
        }
        float nm = fmaxf(m, s);
        float pj = __expf(s - nm);
        if (nm > m) {
            float c = __expf(m - nm);
            l *= c;
            #pragma unroll
            for (int d = 0; d < cDH; ++d) o[d] *= c;
        }
        m = nm;
        l += pj;
        const bf16x8* vr = (const bf16x8*)(sV + j * cDH);
        #pragma unroll
        for (int c = 0; c < 8; ++c) {
            bf16x8 vv = vr[c];
            #pragma unroll
            for (int u = 0; u < 8; ++u) o[c*8+u] += pj * (float)vv[u];
        }
    }
    const int pi = ((b * cHEADS + h) * NJT + jt) * cSEQ + tid;
    ml[pi * 2]     = m;
    ml[pi * 2 + 1] = l;
    bf16* orow = op + (size_t)pi * cDH;
    #pragma unroll
    for (int d = 0; d < cDH; ++d) orow[d] = (bf16)o[d];
}

// ---------------- attention part 2: merge 4 key-tile partials ----------------
__global__ __launch_bounds__(256) void attn_merge_kernel(
    const bf16* __restrict__ op, const float* __restrict__ ml,
    bf16* __restrict__ attn_o)
{
    int idx = blockIdx.x * 256 + threadIdx.x;   // over 192*169*8
    if (idx >= cB * cHEADS * cSEQ * 8) return;
    int d8 = idx & 7;
    int t  = idx >> 3;
    int q  = t % cSEQ;
    int bh = t / cSEQ;
    int b = bh / cHEADS, h = bh - b * cHEADS;
    const int pbase = (bh * NJT) * cSEQ + q;    // + jt*cSEQ per tile

    float ms[NJT], ls[NJT], mstar = -1e30f;
    #pragma unroll
    for (int j = 0; j < NJT; ++j) {
        ms[j] = ml[(pbase + j * cSEQ) * 2];
        ls[j] = ml[(pbase + j * cSEQ) * 2 + 1];
        mstar = fmaxf(mstar, ms[j]);
    }
    float den = 0.f, acc[8];
    #pragma unroll
    for (int u = 0; u < 8; ++u) acc[u] = 0.f;
    #pragma unroll
    for (int j = 0; j < NJT; ++j) {
        float w = __expf(ms[j] - mstar);
        den += w * ls[j];
        bf16x8 v = *(const bf16x8*)(op + (size_t)(pbase + j * cSEQ) * cDH + d8 * 8);
        #pragma unroll
        for (int u = 0; u < 8; ++u) acc[u] += w * (float)v[u];
    }
    float inv = 1.0f / den;
    bf16* outp = attn_o + ((size_t)(b * cSEQ + q)) * cE + h * cDH + d8 * 8;
    #pragma unroll
    for (int u = 0; u < 8; ++u) outp[u] = (bf16)(acc[u] * inv);
}

// ---------------- vis_mask: 2704 ones (read back as float32) ----------------
__global__ __launch_bounds__(256) void mask_kernel(float* __restrict__ out)
{
    int i = blockIdx.x * 256 + threadIdx.x;
    if (i < cN) out[i] = 1.0f;
}

// ---------------- host orchestration ----------------
extern "C" void kernel_launch(void* const* d_in, const int* in_sizes, int n_in,
                              void* d_out, int out_size, void* d_ws, size_t ws_size,
                              hipStream_t stream)
{
    const float* pixel   = (const float*)d_in[0];
    const float* patch_W = (const float*)d_in[1];
    const float* patch_b = (const float*)d_in[2];
    const float* row_emb = (const float*)d_in[3];
    const float* col_emb = (const float*)d_in[4];
    const float* cls     = (const float*)d_in[5];
    const float* ln1_g   = (const float*)d_in[6];
    const float* ln1_b   = (const float*)d_in[7];
    const float* in_w    = (const float*)d_in[8];
    const float* in_b    = (const float*)d_in[9];
    const float* out_w   = (const float*)d_in[10];
    const float* out_b   = (const float*)d_in[11];
    const float* ln2_g   = (const float*)d_in[12];
    const float* ln2_b   = (const float*)d_in[13];
    const float* mlp_w1  = (const float*)d_in[14];
    const float* mlp_b1  = (const float*)d_in[15];
    const float* mlp_w2  = (const float*)d_in[16];
    const float* mlp_b2  = (const float*)d_in[17];
    const float* fin_g   = (const float*)d_in[18];
    const float* fin_b   = (const float*)d_in[19];
    const float* br_w1   = (const float*)d_in[20];
    const float* br_b1   = (const float*)d_in[21];
    const float* br_w2   = (const float*)d_in[22];
    const float* br_b2   = (const float*)d_in[23];
    const float* br_g    = (const float*)d_in[24];
    const float* br_b    = (const float*)d_in[25];

    // workspace layout; top = 70,385,664 B
    char* ws = (char*)d_ws;
    float* x      = (float*)(ws);                        // [2816,768] f32,  8,650,752
    bf16*  xn     = (bf16 *)(ws + 8650752);              // [2816,768] bf16, 4,325,376
    bf16*  qkv    = (bf16 *)(ws + 12976128);             // [2816,2304] bf16, 12,976,128
    bf16*  attn_o = (bf16 *)(ws + 25952256);             // [2816,768] bf16, 4,325,376
    bf16*  hmlp   = (bf16 *)(ws + 30277632);             // [2816,3072] bf16, 17,301,504
    bf16*  hb1    = (bf16 *)(ws + 47579136);             // [2816,1536] bf16, 8,650,752
    bf16*  wbuf   = (bf16 *)(ws + 56229888);             // 7,077,888 elems = 14,155,776 B
    // aliases (disjoint lifetimes):
    float* pe     = (float*)(ws + 30277632);             // [2688,768] f32 (patch phase)
    bf16*  Apatch = (bf16 *)(ws + 47579136);             // [2688,768] bf16 (patch phase)
    bf16*  att_op = (bf16 *)(ws + 30277632);             // 16,613,376 B (attn phase, pre-MLP1)
    float* att_ml = (float*)(ws + 47579136);             // 1,038,336 B  (attn phase, pre-branch)
    float* h2     = (float*)(ws + 12976128);             // [2816,2048] f32 (branch phase)

    auto conv = [&](const float* src, bf16* dst, int n) {
        int n4 = n / 4;
        f2b_kernel<<<(n4 + 255) / 256, 256, 0, stream>>>(src, dst, n4);
    };
    auto gemm = [&](const bf16* Abf, const bf16* Wbf, const float* bias,
                    const float* resid, float* oF, bf16* oB,
                    int M, int N, int K, int epi) {
        dim3 g(N / 128, M / 128);
        gemm_bt_kernel<<<g, 256, 0, stream>>>(Abf, Wbf, bias, resid, oF, oB, M, N, K, epi);
    };
    auto gemm64 = [&](const bf16* Abf, const bf16* Wbf, const float* bias,
                      const float* resid, float* oF, bf16* oB,
                      int M, int N, int K, int epi) {
        dim3 g(N / 64, M / 128);
        gemm_bt64_kernel<<<g, 256, 0, stream>>>(Abf, Wbf, bias, resid, oF, oB, M, N, K, epi);
    };

    // ---- patch embed ----
    patchify_kernel<<<(cB * cNPAT * cE + 255) / 256, 256, 0, stream>>>(pixel, Apatch);
    conv(patch_W, wbuf, cE * cE);
    gemm64(Apatch, wbuf, patch_b, nullptr, pe, nullptr, cB * cNPAT, cE, cE, EPI_F32);
    assemble_kernel<<<(cN * cE + 255) / 256, 256, 0, stream>>>(pe, row_emb, col_emb, cls, x);

    const int merge_n = cB * cHEADS * cSEQ * 8;
    // wbuf per-layer offsets
    bf16* w_qkv = wbuf;
    bf16* w_out = wbuf + 1769472;
    bf16* w_m1  = wbuf + 2359296;
    bf16* w_m2  = wbuf + 4718592;

    // ---- transformer layers ----
    for (int l = 0; l < cL; ++l) {
        conv4_kernel<<<(1769472 + 255) / 256, 256, 0, stream>>>(
            in_w  + (size_t)l * 3 * cE * cE,
            out_w + (size_t)l * cE * cE,
            mlp_w1 + (size_t)l * cMLP * cE,
            mlp_w2 + (size_t)l * cE * cMLP, wbuf);
        ln_kernel<<<cN, 256, 0, stream>>>(x, ln1_g + l * cE, ln1_b + l * cE, xn, nullptr, cE);
        gemm(xn, w_qkv, in_b + (size_t)l * 3 * cE, nullptr, nullptr, qkv, cMp, 3 * cE, cE, EPI_BF16);
        attn_part_kernel<<<dim3(cHEADS, cB, NJT), 192, 0, stream>>>(qkv, att_op, att_ml);
        attn_merge_kernel<<<(merge_n + 255) / 256, 256, 0, stream>>>(att_op, att_ml, attn_o);
        gemm64(attn_o, w_out, out_b + (size_t)l * cE, x, x, nullptr, cMp, cE, cE, EPI_RES);
        ln_kernel<<<cN, 256, 0, stream>>>(x, ln2_g + l * cE, ln2_b + l * cE, xn, nullptr, cE);
        gemm(xn, w_m1, mlp_b1 + (size_t)l * cMLP, nullptr, nullptr, hmlp, cMp, cMLP, cE, EPI_GELU_BF16);
        gemm64(hmlp, w_m2, mlp_b2 + (size_t)l * cE, x, x, nullptr, cMp, cE, cMLP, EPI_RES);
    }

    // ---- final LN + branch head ----
    ln_kernel<<<cN, 256, 0, stream>>>(x, fin_g, fin_b, xn, nullptr, cE);
    conv(br_w1, wbuf, 2 * cE * cE);
    conv(br_w2, wbuf + 1179648, cOUT * 2 * cE);
    gemm(xn, wbuf, br_b1, nullptr, nullptr, hb1, cMp, 2 * cE, cE, EPI_GELU_BF16);
    gemm(hb1, wbuf + 1179648, br_b2, nullptr, h2, nullptr, cMp, cOUT, 2 * cE, EPI_F32);
    ln_kernel<<<cN, 256, 0, stream>>>(h2, br_g, br_b, nullptr, (float*)d_out, cOUT);

    // ---- vis_mask ----
    mask_kernel<<<(cN + 255) / 256, 256, 0, stream>>>((float*)d_out + (size_t)cN * cOUT);
}

// Round 2
// 2819.646 us; speedup vs baseline: 1.2587x; 1.1447x over previous
//
#include <hip/hip_runtime.h>
#include <hip/hip_bf16.h>
#include <math.h>

typedef __bf16 bf16;
typedef __attribute__((ext_vector_type(8))) __bf16 bf16x8;
typedef __attribute__((ext_vector_type(4))) __bf16 bf16x4;
typedef __attribute__((ext_vector_type(4))) float f32x4;

// ---------------- constants ----------------
constexpr int cB = 16, cC = 3, cH = 64, cW = 672;
constexpr int cP = 16, cE = 768, cHEADS = 12, cL = 12;
constexpr int cMLP = 3072, cOUT = 2048;
constexpr int cPH = 4, cPW = 42, cNPAT = 168, cSEQ = 169;
constexpr int cN = cB * cSEQ;          // 2704 packed rows
constexpr int cMp = 2816;              // padded to 22*128
constexpr int cDH = 64;
constexpr int NJT = 2, KT = 96;        // 2 key tiles of 96 (keys padded 169->192)

enum { EPI_F32 = 0, EPI_RES = 1, EPI_GELU_BF16 = 2, EPI_BF16 = 3 };

// ---------------- async global->LDS 16B per lane ----------------
// LDS side is wave-uniform base + lane*16 (HW-added); global side is per-lane gather.
__device__ __forceinline__ void async16(const bf16* g, bf16* l) {
    __builtin_amdgcn_global_load_lds(
        (__attribute__((address_space(1))) void*)(void*)g,
        (__attribute__((address_space(3))) void*)(void*)l,
        16, 0, 0);
}

// bijective XCD-chunk swizzle (m204): consecutive HW block ids round-robin XCDs;
// remap so each XCD owns a contiguous chunk of the linear grid -> A-panel L2 reuse.
__device__ __forceinline__ int xcd_swz(int orig, int nwg) {
    int q = nwg >> 3, r = nwg & 7;
    int xcd = orig & 7, idx = orig >> 3;
    return (xcd < r ? xcd * (q + 1) : r * (q + 1) + (xcd - r) * q) + idx;
}

// ---------------- patchify: pixels -> bf16 patch matrix [2688, 768] ----------------
__global__ __launch_bounds__(256) void patchify_kernel(
    const float* __restrict__ px, bf16* __restrict__ Ap)
{
    int idx = blockIdx.x * 256 + threadIdx.x;            // over 2688*768
    if (idx >= cB * cNPAT * cE) return;
    int gp = idx / cE, e = idx - gp * cE;
    int b = gp / cNPAT, p = gp - b * cNPAT;
    int ph = p / cPW, pw = p - ph * cPW;
    int c = e >> 8, r = (e >> 4) & 15, col = e & 15;
    float v = px[(((size_t)b * cC + c) * cH + (ph * cP + r)) * cW + pw * cP + col];
    Ap[idx] = (bf16)v;
}

// ---------------- assemble: cls + pe + pos -> x fp32 [2704, 768] ----------------
__global__ __launch_bounds__(256) void assemble_kernel(
    const float* __restrict__ pe, const float* __restrict__ row_emb,
    const float* __restrict__ col_emb, const float* __restrict__ cls,
    float* __restrict__ x)
{
    int idx = blockIdx.x * 256 + threadIdx.x;            // over 2704*768
    if (idx >= cN * cE) return;
    int row = idx / cE, e = idx - row * cE;
    int b = row / cSEQ, s = row - b * cSEQ;
    float v;
    if (s == 0) {
        v = cls[e];
    } else {
        int p = s - 1, ph = p / cPW, pw = p - ph * cPW;
        float pos = (e < 384) ? row_emb[ph * 384 + e] : col_emb[pw * 384 + e - 384];
        v = pe[((size_t)b * cNPAT + p) * cE + e] + pos;
    }
    x[idx] = v;
}

// ---------------- fp32 -> bf16 convert (x4 vectorized) ----------------
__global__ __launch_bounds__(256) void f2b_kernel(
    const float* __restrict__ in, bf16* __restrict__ out, int n4)
{
    int i = blockIdx.x * 256 + threadIdx.x;
    if (i >= n4) return;
    f32x4 v = ((const f32x4*)in)[i];
    bf16x4 r;
    r[0] = (bf16)v[0]; r[1] = (bf16)v[1]; r[2] = (bf16)v[2]; r[3] = (bf16)v[3];
    ((bf16x4*)out)[i] = r;
}

// ---------------- batched layer-weight conversion: 4 segments -> wbuf ----------------
// seg sizes (f32x4 units): in_w 442368, out_w 147456, mlp_w1 589824, mlp_w2 589824
__global__ __launch_bounds__(256) void conv4_kernel(
    const float* __restrict__ s0, const float* __restrict__ s1,
    const float* __restrict__ s2, const float* __restrict__ s3,
    bf16* __restrict__ dst)
{
    int i = blockIdx.x * 256 + threadIdx.x;
    if (i >= 1769472) return;
    const float* src; size_t off;
    if (i < 442368)       { src = s0 + (size_t)i * 4;             off = (size_t)i * 4; }
    else if (i < 589824)  { int j = i - 442368;  src = s1 + (size_t)j * 4; off = 1769472 + (size_t)j * 4; }
    else if (i < 1179648) { int j = i - 589824;  src = s2 + (size_t)j * 4; off = 2359296 + (size_t)j * 4; }
    else                  { int j = i - 1179648; src = s3 + (size_t)j * 4; off = 4718592 + (size_t)j * 4; }
    f32x4 v = *(const f32x4*)src;
    bf16x4 r;
    r[0] = (bf16)v[0]; r[1] = (bf16)v[1]; r[2] = (bf16)v[2]; r[3] = (bf16)v[3];
    *(bf16x4*)(dst + off) = r;
}

// ---------------- layernorm over D cols; out bf16 or fp32 ----------------
__global__ __launch_bounds__(256) void ln_kernel(
    const float* __restrict__ x, const float* __restrict__ g,
    const float* __restrict__ bta, bf16* __restrict__ outB,
    float* __restrict__ outF, int D)
{
    const int row = blockIdx.x;
    const float* xr = x + (size_t)row * D;
    float s = 0.f, s2 = 0.f;
    for (int d = threadIdx.x; d < D; d += 256) { float v = xr[d]; s += v; s2 += v * v; }
    #pragma unroll
    for (int off = 32; off > 0; off >>= 1) {
        s  += __shfl_down(s, off);
        s2 += __shfl_down(s2, off);
    }
    __shared__ float rs[4], rs2[4];
    if ((threadIdx.x & 63) == 0) { rs[threadIdx.x >> 6] = s; rs2[threadIdx.x >> 6] = s2; }
    __syncthreads();
    s = rs[0] + rs[1] + rs[2] + rs[3];
    s2 = rs2[0] + rs2[1] + rs2[2] + rs2[3];
    const float mean = s / D;
    const float rstd = rsqrtf(s2 / D - mean * mean + 1e-5f);
    for (int d = threadIdx.x; d < D; d += 256) {
        float v = (xr[d] - mean) * rstd * g[d] + bta[d];
        if (outB) outB[(size_t)row * D + d] = (bf16)v;
        else      outF[(size_t)row * D + d] = v;
    }
}

// ---------------- bf16 MFMA GEMM: out = epi(A[M,K] @ W[N,K]^T + bias) ----------------
// 128x128 tile, BK=64, DOUBLE-buffered LDS (64 KB), global_load_lds width=16.
// LDS layout XOR-swizzled: row r, physical 16B-chunk c holds global chunk c^(r&7).
__global__ __launch_bounds__(256, 2) void gemm_bt_kernel(
    const bf16* __restrict__ A, const bf16* __restrict__ Bw,
    const float* __restrict__ bias, const float* __restrict__ res,
    float* __restrict__ outF, bf16* __restrict__ outB,
    int M, int N, int K, int epi)
{
    __shared__ bf16 sA[2 * 128 * 64];    // 32 KB
    __shared__ bf16 sB[2 * 128 * 64];    // 32 KB

    const int tid  = threadIdx.x;
    const int lane = tid & 63;
    const int wave = tid >> 6;

    const int nwg  = gridDim.x * gridDim.y;
    const int swz  = xcd_swz(blockIdx.y * gridDim.x + blockIdx.x, nwg);
    const int bm = (swz / gridDim.x) * 128;
    const int bn = (swz % gridDim.x) * 128;
    const int wm = (wave & 1) * 64;
    const int wn = (wave >> 1) * 64;

    const int r_in = lane >> 3;                    // 0..7
    const int swz_col = ((lane & 7) ^ r_in) * 8;   // global elem offset of this lane's chunk

    const int m_lo = lane & 15;
    const int quad = lane >> 4;

    f32x4 acc[4][4];
    #pragma unroll
    for (int i = 0; i < 4; ++i)
        #pragma unroll
        for (int j = 0; j < 4; ++j) {
            f32x4 z = {0.f, 0.f, 0.f, 0.f};
            acc[i][j] = z;
        }

    const int nk = K >> 6;

    auto stage = [&](int kt, int buf) {
        const int k0 = kt << 6;
        const bf16* gA = A  + (size_t)(bm + wave * 32 + r_in) * K + k0 + swz_col;
        const bf16* gB = Bw + (size_t)(bn + wave * 32 + r_in) * K + k0 + swz_col;
        bf16* lA = sA + buf * 8192 + (wave * 32) * 64;
        bf16* lB = sB + buf * 8192 + (wave * 32) * 64;
        #pragma unroll
        for (int d = 0; d < 4; ++d) {
            async16(gA + (size_t)(d * 8) * K, lA + d * 512);
            async16(gB + (size_t)(d * 8) * K, lB + d * 512);
        }
    };

    stage(0, 0);

    for (int kt = 0; kt < nk; ++kt) {
        __syncthreads();
        if (kt + 1 < nk) stage(kt + 1, (kt + 1) & 1);

        const bf16* bufA = sA + (kt & 1) * 8192;
        const bf16* bufB = sB + (kt & 1) * 8192;

        bf16x8 af[2][4], bfr[2][4];
        #pragma unroll
        for (int j = 0; j < 2; ++j)
            #pragma unroll
            for (int i = 0; i < 4; ++i) {
                const int c = ((quad + j * 4) ^ (m_lo & 7)) * 8;   // swizzled chunk
                af[j][i]  = *(const bf16x8*)(bufA + (wm + i * 16 + m_lo) * 64 + c);
                bfr[j][i] = *(const bf16x8*)(bufB + (wn + i * 16 + m_lo) * 64 + c);
            }
        #pragma unroll
        for (int j = 0; j < 2; ++j)
            #pragma unroll
            for (int mi = 0; mi < 4; ++mi)
                #pragma unroll
                for (int ni = 0; ni < 4; ++ni)
                    acc[mi][ni] = __builtin_amdgcn_mfma_f32_16x16x32_bf16(
                        af[j][mi], bfr[j][ni], acc[mi][ni], 0, 0, 0);
    }

    // epilogue: C/D layout col=lane&15, row=quad*4+r  (verified m89/m91)
    #pragma unroll
    for (int mi = 0; mi < 4; ++mi) {
        #pragma unroll
        for (int ni = 0; ni < 4; ++ni) {
            #pragma unroll
            for (int r = 0; r < 4; ++r) {
                int row = bm + wm + mi * 16 + quad * 4 + r;
                int col = bn + wn + ni * 16 + m_lo;
                float v = acc[mi][ni][r] + bias[col];
                if (epi == EPI_RES) {
                    v += res[(size_t)row * N + col];
                    outF[(size_t)row * N + col] = v;
                } else if (epi == EPI_GELU_BF16) {
                    v = v * 0.5f * (1.0f + erff(v * 0.70710678118f));
                    outB[(size_t)row * N + col] = (bf16)v;
                } else if (epi == EPI_BF16) {
                    outB[(size_t)row * N + col] = (bf16)v;
                } else {
                    outF[(size_t)row * N + col] = v;
                }
            }
        }
    }
}

// ---------------- narrow-N variant: BM=128, BN=64, 3 blocks/CU ----------------
__global__ __launch_bounds__(256, 3) void gemm_bt64_kernel(
    const bf16* __restrict__ A, const bf16* __restrict__ Bw,
    const float* __restrict__ bias, const float* __restrict__ res,
    float* __restrict__ outF, bf16* __restrict__ outB,
    int M, int N, int K, int epi)
{
    __shared__ bf16 sA[2 * 128 * 64];    // 32 KB
    __shared__ bf16 sB[2 * 64 * 64];     // 16 KB

    const int tid  = threadIdx.x;
    const int lane = tid & 63;
    const int wave = tid >> 6;

    const int nwg  = gridDim.x * gridDim.y;
    const int swz  = xcd_swz(blockIdx.y * gridDim.x + blockIdx.x, nwg);
    const int bm = (swz / gridDim.x) * 128;
    const int bn = (swz % gridDim.x) * 64;
    const int wm = (wave & 1) * 64;      // 2x2 wave grid, wave tile 64x32
    const int wn = (wave >> 1) * 32;

    const int r_in = lane >> 3;                    // 0..7
    const int swz_col = ((lane & 7) ^ r_in) * 8;
    const int m_lo = lane & 15;
    const int quad = lane >> 4;

    f32x4 acc[4][2];
    #pragma unroll
    for (int i = 0; i < 4; ++i)
        #pragma unroll
        for (int j = 0; j < 2; ++j) {
            f32x4 z = {0.f, 0.f, 0.f, 0.f};
            acc[i][j] = z;
        }

    const int nk = K >> 6;

    auto stage = [&](int kt, int buf) {
        const int k0 = kt << 6;
        const bf16* gA = A  + (size_t)(bm + wave * 32 + r_in) * K + k0 + swz_col;
        bf16* lA = sA + buf * 8192 + (wave * 32) * 64;
        #pragma unroll
        for (int d = 0; d < 4; ++d)
            async16(gA + (size_t)(d * 8) * K, lA + d * 512);
        const bf16* gB = Bw + (size_t)(bn + wave * 16 + r_in) * K + k0 + swz_col;
        bf16* lB = sB + buf * 4096 + (wave * 16) * 64;
        #pragma unroll
        for (int d = 0; d < 2; ++d)
            async16(gB + (size_t)(d * 8) * K, lB + d * 512);
    };

    stage(0, 0);

    for (int kt = 0; kt < nk; ++kt) {
        __syncthreads();
        if (kt + 1 < nk) stage(kt + 1, (kt + 1) & 1);

        const bf16* bufA = sA + (kt & 1) * 8192;
        const bf16* bufB = sB + (kt & 1) * 4096;

        bf16x8 af[2][4], bfr[2][2];
        #pragma unroll
        for (int j = 0; j < 2; ++j) {
            #pragma unroll
            for (int i = 0; i < 4; ++i) {
                const int c = ((quad + j * 4) ^ (m_lo & 7)) * 8;
                af[j][i] = *(const bf16x8*)(bufA + (wm + i * 16 + m_lo) * 64 + c);
            }
            #pragma unroll
            for (int i = 0; i < 2; ++i) {
                const int c = ((quad + j * 4) ^ (m_lo & 7)) * 8;
                bfr[j][i] = *(const bf16x8*)(bufB + (wn + i * 16 + m_lo) * 64 + c);
            }
        }
        #pragma unroll
        for (int j = 0; j < 2; ++j)
            #pragma unroll
            for (int mi = 0; mi < 4; ++mi)
                #pragma unroll
                for (int ni = 0; ni < 2; ++ni)
                    acc[mi][ni] = __builtin_amdgcn_mfma_f32_16x16x32_bf16(
                        af[j][mi], bfr[j][ni], acc[mi][ni], 0, 0, 0);
    }

    #pragma unroll
    for (int mi = 0; mi < 4; ++mi) {
        #pragma unroll
        for (int ni = 0; ni < 2; ++ni) {
            #pragma unroll
            for (int r = 0; r < 4; ++r) {
                int row = bm + wm + mi * 16 + quad * 4 + r;
                int col = bn + wn + ni * 16 + m_lo;
                float v = acc[mi][ni][r] + bias[col];
                if (epi == EPI_RES) {
                    v += res[(size_t)row * N + col];
                    outF[(size_t)row * N + col] = v;
                } else if (epi == EPI_GELU_BF16) {
                    v = v * 0.5f * (1.0f + erff(v * 0.70710678118f));
                    outB[(size_t)row * N + col] = (bf16)v;
                } else if (epi == EPI_BF16) {
                    outB[(size_t)row * N + col] = (bf16)v;
                } else {
                    outF[(size_t)row * N + col] = v;
                }
            }
        }
    }
}

// ---------------- MFMA attention: block per (head, image, key-half) ----------------
// 6 waves x 64; wave owns 32 q-rows (169 padded to 192). Block covers 96 keys.
// S = Q K^T via mfma 16x16x32 (Q frags from global, K staged xor-swizzled in LDS).
// Masked softmax with per-row shuffle reduce; P -> bf16 -> per-wave LDS tile.
// O = P V with V^T staged in LDS. Stores UNNORMALIZED partial O + (m,l) per row;
// attn_merge_kernel (NJT=2) combines the two key-halves.
// Fragment layouts mirror gemm_bt_kernel exactly (A/B: row=lane&15, k=quad*8;
// C/D: row=quad*4+r, col=lane&15).
__global__ __launch_bounds__(384) void attn_mfma_kernel(
    const bf16* __restrict__ qkv, bf16* __restrict__ op, float* __restrict__ ml)
{
    __shared__ bf16 sK[KT * cDH];          // 12 KB, xor-swizzled rows
    __shared__ bf16 sVT[cDH * 104];        // 13 KB, V^T, padded stride 104 (2-way banks = free)
    __shared__ bf16 sP[6 * 32 * 104];      // 39 KB, per-wave P tiles
    // total 64 KB exactly -> 2 blocks/CU, all 384 blocks co-resident

    const int h = blockIdx.x, b = blockIdx.y, kt = blockIdx.z;
    const int tid  = threadIdx.x;
    const int lane = tid & 63, wave = tid >> 6;
    const int m_lo = lane & 15, quad = lane >> 4;
    const int K0 = kt * KT;
    const int rowb = b * cSEQ;

    // ---- stage K rows K0..K0+95 (clamped; padded keys masked later), async ----
    {
        const int r_in = lane >> 3;
        const int swz = ((lane & 7) ^ r_in) * 8;
        #pragma unroll
        for (int d = 0; d < 2; ++d) {
            int key = K0 + wave * 16 + d * 8 + r_in;
            int grow = rowb + min(key, cSEQ - 1);
            async16(qkv + (size_t)grow * (3 * cE) + cE + h * cDH + swz,
                    sK + (wave * 16 + d * 8) * cDH);
        }
    }
    // ---- stage V^T (d-major): coalesced u32 global reads, scalar LDS writes ----
    for (int idx = tid; idx < KT * 32; idx += 384) {
        int key = idx >> 5, dp = idx & 31;
        int grow = rowb + min(K0 + key, cSEQ - 1);
        unsigned v = *(const unsigned*)(qkv + (size_t)grow * (3 * cE) + 2 * cE + h * cDH + dp * 2);
        sVT[(dp * 2) * 104 + key]     = ((const bf16*)&v)[0];
        sVT[(dp * 2 + 1) * 104 + key] = ((const bf16*)&v)[1];
    }
    // ---- Q fragments straight from global (row-clamped for q-padding) ----
    bf16x8 qf[2][2];
    #pragma unroll
    for (int j = 0; j < 2; ++j)
        #pragma unroll
        for (int s = 0; s < 2; ++s) {
            int qrow = min(wave * 32 + j * 16 + m_lo, cSEQ - 1);
            qf[j][s] = *(const bf16x8*)(qkv + (size_t)(rowb + qrow) * (3 * cE)
                                        + h * cDH + s * 32 + quad * 8);
        }
    __syncthreads();   // drains async K DMAs (vmcnt 0) + VT writes

    // ---- S = Q K^T : 2 q-subtiles x 6 key-tiles, K-dim 64 = 2 mfma steps ----
    f32x4 sc[2][6];
    #pragma unroll
    for (int j = 0; j < 2; ++j)
        #pragma unroll
        for (int t = 0; t < 6; ++t) {
            f32x4 z = {0.f, 0.f, 0.f, 0.f};
            sc[j][t] = z;
        }
    #pragma unroll
    for (int t = 0; t < 6; ++t)
        #pragma unroll
        for (int s2 = 0; s2 < 2; ++s2) {
            const int c = ((quad + s2 * 4) ^ (m_lo & 7)) * 8;
            bf16x8 kf = *(const bf16x8*)(sK + (t * 16 + m_lo) * cDH + c);
            #pragma unroll
            for (int j = 0; j < 2; ++j)
                sc[j][t] = __builtin_amdgcn_mfma_f32_16x16x32_bf16(qf[j][s2], kf, sc[j][t], 0, 0, 0);
        }

    // ---- masked softmax; rows q = 16j+quad*4+r, cols key = 16t+m_lo ----
    bf16* sPw = sP + wave * (32 * 104);
    #pragma unroll
    for (int j = 0; j < 2; ++j) {
        float mr[4] = {-1e30f, -1e30f, -1e30f, -1e30f};
        #pragma unroll
        for (int t = 0; t < 6; ++t) {
            const bool pad = (K0 + t * 16 + m_lo) >= cSEQ;
            #pragma unroll
            for (int r = 0; r < 4; ++r) {
                float v = sc[j][t][r] * 0.125f;       // 1/sqrt(64)
                if (pad) v = -1e30f;
                sc[j][t][r] = v;
                mr[r] = fmaxf(mr[r], v);
            }
        }
        #pragma unroll
        for (int r = 0; r < 4; ++r) {
            mr[r] = fmaxf(mr[r], __shfl_xor(mr[r], 1));
            mr[r] = fmaxf(mr[r], __shfl_xor(mr[r], 2));
            mr[r] = fmaxf(mr[r], __shfl_xor(mr[r], 4));
            mr[r] = fmaxf(mr[r], __shfl_xor(mr[r], 8));
        }
        float lr[4] = {0.f, 0.f, 0.f, 0.f};
        #pragma unroll
        for (int t = 0; t < 6; ++t)
            #pragma unroll
            for (int r = 0; r < 4; ++r) {
                float p = __expf(sc[j][t][r] - mr[r]);
                lr[r] += p;
                sPw[(j * 16 + quad * 4 + r) * 104 + t * 16 + m_lo] = (bf16)p;
            }
        #pragma unroll
        for (int r = 0; r < 4; ++r) {
            lr[r] += __shfl_xor(lr[r], 1);
            lr[r] += __shfl_xor(lr[r], 2);
            lr[r] += __shfl_xor(lr[r], 4);
            lr[r] += __shfl_xor(lr[r], 8);
        }
        if (m_lo == 0) {
            #pragma unroll
            for (int r = 0; r < 4; ++r) {
                int qg = wave * 32 + j * 16 + quad * 4 + r;
                if (qg < cSEQ) {
                    int pi = ((b * cHEADS + h) * NJT + kt) * cSEQ + qg;
                    ml[pi * 2]     = mr[r];
                    ml[pi * 2 + 1] = lr[r];
                }
            }
        }
    }

    // ---- O = P V : 96 keys = exactly 3 mfma k-steps (no pad reads) ----
    f32x4 oc[2][4];
    #pragma unroll
    for (int j = 0; j < 2; ++j)
        #pragma unroll
        for (int dt = 0; dt < 4; ++dt) {
            f32x4 z = {0.f, 0.f, 0.f, 0.f};
            oc[j][dt] = z;
        }
    #pragma unroll
    for (int s3 = 0; s3 < 3; ++s3) {
        bf16x8 pa[2], vf[4];
        #pragma unroll
        for (int j = 0; j < 2; ++j)
            pa[j] = *(const bf16x8*)(sPw + (j * 16 + m_lo) * 104 + s3 * 32 + quad * 8);
        #pragma unroll
        for (int dt = 0; dt < 4; ++dt)
            vf[dt] = *(const bf16x8*)(sVT + (dt * 16 + m_lo) * 104 + s3 * 32 + quad * 8);
        #pragma unroll
        for (int j = 0; j < 2; ++j)
            #pragma unroll
            for (int dt = 0; dt < 4; ++dt)
                oc[j][dt] = __builtin_amdgcn_mfma_f32_16x16x32_bf16(pa[j], vf[dt], oc[j][dt], 0, 0, 0);
    }

    // ---- store unnormalized partial O (merge kernel normalizes) ----
    #pragma unroll
    for (int j = 0; j < 2; ++j)
        #pragma unroll
        for (int dt = 0; dt < 4; ++dt)
            #pragma unroll
            for (int r = 0; r < 4; ++r) {
                int qg = wave * 32 + j * 16 + quad * 4 + r;
                if (qg < cSEQ) {
                    int pi = ((b * cHEADS + h) * NJT + kt) * cSEQ + qg;
                    op[(size_t)pi * cDH + dt * 16 + m_lo] = (bf16)oc[j][dt][r];
                }
            }
}

// ---------------- attention part 2: merge 2 key-half partials ----------------
__global__ __launch_bounds__(256) void attn_merge_kernel(
    const bf16* __restrict__ op, const float* __restrict__ ml,
    bf16* __restrict__ attn_o)
{
    int idx = blockIdx.x * 256 + threadIdx.x;   // over 192*169*8
    if (idx >= cB * cHEADS * cSEQ * 8) return;
    int d8 = idx & 7;
    int t  = idx >> 3;
    int q  = t % cSEQ;
    int bh = t / cSEQ;
    int b = bh / cHEADS, h = bh - b * cHEADS;
    const int pbase = (bh * NJT) * cSEQ + q;    // + jt*cSEQ per tile

    float ms[NJT], ls[NJT], mstar = -1e30f;
    #pragma unroll
    for (int j = 0; j < NJT; ++j) {
        ms[j] = ml[(pbase + j * cSEQ) * 2];
        ls[j] = ml[(pbase + j * cSEQ) * 2 + 1];
        mstar = fmaxf(mstar, ms[j]);
    }
    float den = 0.f, acc[8];
    #pragma unroll
    for (int u = 0; u < 8; ++u) acc[u] = 0.f;
    #pragma unroll
    for (int j = 0; j < NJT; ++j) {
        float w = __expf(ms[j] - mstar);
        den += w * ls[j];
        bf16x8 v = *(const bf16x8*)(op + (size_t)(pbase + j * cSEQ) * cDH + d8 * 8);
        #pragma unroll
        for (int u = 0; u < 8; ++u) acc[u] += w * (float)v[u];
    }
    float inv = 1.0f / den;
    bf16* outp = attn_o + ((size_t)(b * cSEQ + q)) * cE + h * cDH + d8 * 8;
    #pragma unroll
    for (int u = 0; u < 8; ++u) outp[u] = (bf16)(acc[u] * inv);
}

// ---------------- vis_mask: 2704 ones (read back as float32) ----------------
__global__ __launch_bounds__(256) void mask_kernel(float* __restrict__ out)
{
    int i = blockIdx.x * 256 + threadIdx.x;
    if (i < cN) out[i] = 1.0f;
}

// ---------------- host orchestration ----------------
extern "C" void kernel_launch(void* const* d_in, const int* in_sizes, int n_in,
                              void* d_out, int out_size, void* d_ws, size_t ws_size,
                              hipStream_t stream)
{
    const float* pixel   = (const float*)d_in[0];
    const float* patch_W = (const float*)d_in[1];
    const float* patch_b = (const float*)d_in[2];
    const float* row_emb = (const float*)d_in[3];
    const float* col_emb = (const float*)d_in[4];
    const float* cls     = (const float*)d_in[5];
    const float* ln1_g   = (const float*)d_in[6];
    const float* ln1_b   = (const float*)d_in[7];
    const float* in_w    = (const float*)d_in[8];
    const float* in_b    = (const float*)d_in[9];
    const float* out_w   = (const float*)d_in[10];
    const float* out_b   = (const float*)d_in[11];
    const float* ln2_g   = (const float*)d_in[12];
    const float* ln2_b   = (const float*)d_in[13];
    const float* mlp_w1  = (const float*)d_in[14];
    const float* mlp_b1  = (const float*)d_in[15];
    const float* mlp_w2  = (const float*)d_in[16];
    const float* mlp_b2  = (const float*)d_in[17];
    const float* fin_g   = (const float*)d_in[18];
    const float* fin_b   = (const float*)d_in[19];
    const float* br_w1   = (const float*)d_in[20];
    const float* br_b1   = (const float*)d_in[21];
    const float* br_w2   = (const float*)d_in[22];
    const float* br_b2   = (const float*)d_in[23];
    const float* br_g    = (const float*)d_in[24];
    const float* br_b    = (const float*)d_in[25];

    // workspace layout; top = 70,385,664 B
    char* ws = (char*)d_ws;
    float* x      = (float*)(ws);                        // [2816,768] f32,  8,650,752
    bf16*  xn     = (bf16 *)(ws + 8650752);              // [2816,768] bf16, 4,325,376
    bf16*  qkv    = (bf16 *)(ws + 12976128);             // [2816,2304] bf16, 12,976,128
    bf16*  attn_o = (bf16 *)(ws + 25952256);             // [2816,768] bf16, 4,325,376
    bf16*  hmlp   = (bf16 *)(ws + 30277632);             // [2816,3072] bf16, 17,301,504
    bf16*  hb1    = (bf16 *)(ws + 47579136);             // [2816,1536] bf16, 8,650,752
    bf16*  wbuf   = (bf16 *)(ws + 56229888);             // 7,077,888 elems = 14,155,776 B
    // aliases (disjoint lifetimes):
    float* pe     = (float*)(ws + 30277632);             // [2688,768] f32 (patch phase)
    bf16*  Apatch = (bf16 *)(ws + 47579136);             // [2688,768] bf16 (patch phase)
    bf16*  att_op = (bf16 *)(ws + 30277632);             // 8.3 MB used (attn phase, pre-MLP1)
    float* att_ml = (float*)(ws + 47579136);             // 519 KB used (attn phase, pre-branch)
    float* h2     = (float*)(ws + 12976128);             // [2816,2048] f32 (branch phase)

    auto conv = [&](const float* src, bf16* dst, int n) {
        int n4 = n / 4;
        f2b_kernel<<<(n4 + 255) / 256, 256, 0, stream>>>(src, dst, n4);
    };
    auto gemm = [&](const bf16* Abf, const bf16* Wbf, const float* bias,
                    const float* resid, float* oF, bf16* oB,
                    int M, int N, int K, int epi) {
        dim3 g(N / 128, M / 128);
        gemm_bt_kernel<<<g, 256, 0, stream>>>(Abf, Wbf, bias, resid, oF, oB, M, N, K, epi);
    };
    auto gemm64 = [&](const bf16* Abf, const bf16* Wbf, const float* bias,
                      const float* resid, float* oF, bf16* oB,
                      int M, int N, int K, int epi) {
        dim3 g(N / 64, M / 128);
        gemm_bt64_kernel<<<g, 256, 0, stream>>>(Abf, Wbf, bias, resid, oF, oB, M, N, K, epi);
    };

    // ---- patch embed ----
    patchify_kernel<<<(cB * cNPAT * cE + 255) / 256, 256, 0, stream>>>(pixel, Apatch);
    conv(patch_W, wbuf, cE * cE);
    gemm64(Apatch, wbuf, patch_b, nullptr, pe, nullptr, cB * cNPAT, cE, cE, EPI_F32);
    assemble_kernel<<<(cN * cE + 255) / 256, 256, 0, stream>>>(pe, row_emb, col_emb, cls, x);

    const int merge_n = cB * cHEADS * cSEQ * 8;
    // wbuf per-layer offsets
    bf16* w_qkv = wbuf;
    bf16* w_out = wbuf + 1769472;
    bf16* w_m1  = wbuf + 2359296;
    bf16* w_m2  = wbuf + 4718592;

    // ---- transformer layers ----
    for (int l = 0; l < cL; ++l) {
        conv4_kernel<<<(1769472 + 255) / 256, 256, 0, stream>>>(
            in_w  + (size_t)l * 3 * cE * cE,
            out_w + (size_t)l * cE * cE,
            mlp_w1 + (size_t)l * cMLP * cE,
            mlp_w2 + (size_t)l * cE * cMLP, wbuf);
        ln_kernel<<<cN, 256, 0, stream>>>(x, ln1_g + l * cE, ln1_b + l * cE, xn, nullptr, cE);
        gemm(xn, w_qkv, in_b + (size_t)l * 3 * cE, nullptr, nullptr, qkv, cMp, 3 * cE, cE, EPI_BF16);
        attn_mfma_kernel<<<dim3(cHEADS, cB, NJT), 384, 0, stream>>>(qkv, att_op, att_ml);
        attn_merge_kernel<<<(merge_n + 255) / 256, 256, 0, stream>>>(att_op, att_ml, attn_o);
        gemm64(attn_o, w_out, out_b + (size_t)l * cE, x, x, nullptr, cMp, cE, cE, EPI_RES);
        ln_kernel<<<cN, 256, 0, stream>>>(x, ln2_g + l * cE, ln2_b + l * cE, xn, nullptr, cE);
        gemm(xn, w_m1, mlp_b1 + (size_t)l * cMLP, nullptr, nullptr, hmlp, cMp, cMLP, cE, EPI_GELU_BF16);
        gemm64(hmlp, w_m2, mlp_b2 + (size_t)l * cE, x, x, nullptr, cMp, cE, cMLP, EPI_RES);
    }

    // ---- final LN + branch head ----
    ln_kernel<<<cN, 256, 0, stream>>>(x, fin_g, fin_b, xn, nullptr, cE);
    conv(br_w1, wbuf, 2 * cE * cE);
    conv(br_w2, wbuf + 1179648, cOUT * 2 * cE);
    gemm(xn, wbuf, br_b1, nullptr, nullptr, hb1, cMp, 2 * cE, cE, EPI_GELU_BF16);
    gemm(hb1, wbuf + 1179648, br_b2, nullptr, h2, nullptr, cMp, cOUT, 2 * cE, EPI_F32);
    ln_kernel<<<cN, 256, 0, stream>>>(h2, br_g, br_b, nullptr, (float*)d_out, cOUT);

    // ---- vis_mask ----
    mask_kernel<<<(cN + 255) / 256, 256, 0, stream>>>((float*)d_out + (size_t)cN * cOUT);
}

// Round 3
// 2248.407 us; speedup vs baseline: 1.5784x; 1.2541x over previous
//
#include <hip/hip_runtime.h>
#include <hip/hip_bf16.h>
#include <math.h>

typedef __bf16 bf16;
typedef __attribute__((ext_vector_type(8))) __bf16 bf16x8;
typedef __attribute__((ext_vector_type(4))) __bf16 bf16x4;
typedef __attribute__((ext_vector_type(4))) float f32x4;

// ---------------- constants ----------------
constexpr int cB = 16, cC = 3, cH = 64, cW = 672;
constexpr int cP = 16, cE = 768, cHEADS = 12, cL = 12;
constexpr int cMLP = 3072, cOUT = 2048;
constexpr int cPH = 4, cPW = 42, cNPAT = 168, cSEQ = 169;
constexpr int cN = cB * cSEQ;          // 2704 packed rows
constexpr int cMp = 2816;              // padded to 22*128 (= 44*64)
constexpr int cDH = 64;
constexpr int NJT = 2, KT = 96;        // 2 key tiles of 96 (keys padded 169->192)

enum { EPI_F32 = 0, EPI_RES = 1, EPI_GELU_BF16 = 2, EPI_BF16 = 3 };

// ---------------- async global->LDS 16B per lane ----------------
// LDS side is wave-uniform base + lane*16 (HW-added); global side is per-lane gather.
__device__ __forceinline__ void async16(const bf16* g, bf16* l) {
    __builtin_amdgcn_global_load_lds(
        (__attribute__((address_space(1))) void*)(void*)g,
        (__attribute__((address_space(3))) void*)(void*)l,
        16, 0, 0);
}

// bijective XCD-chunk swizzle (m204): consecutive HW block ids round-robin XCDs;
// remap so each XCD owns a contiguous chunk of the linear grid -> A-panel L2 reuse.
__device__ __forceinline__ int xcd_swz(int orig, int nwg) {
    int q = nwg >> 3, r = nwg & 7;
    int xcd = orig & 7, idx = orig >> 3;
    return (xcd < r ? xcd * (q + 1) : r * (q + 1) + (xcd - r) * q) + idx;
}

// ---------------- patchify: pixels -> bf16 patch matrix [2688, 768] ----------------
__global__ __launch_bounds__(256) void patchify_kernel(
    const float* __restrict__ px, bf16* __restrict__ Ap)
{
    int idx = blockIdx.x * 256 + threadIdx.x;            // over 2688*768
    if (idx >= cB * cNPAT * cE) return;
    int gp = idx / cE, e = idx - gp * cE;
    int b = gp / cNPAT, p = gp - b * cNPAT;
    int ph = p / cPW, pw = p - ph * cPW;
    int c = e >> 8, r = (e >> 4) & 15, col = e & 15;
    float v = px[(((size_t)b * cC + c) * cH + (ph * cP + r)) * cW + pw * cP + col];
    Ap[idx] = (bf16)v;
}

// ---------------- assemble: cls + pe + pos -> x fp32 [2704, 768] ----------------
__global__ __launch_bounds__(256) void assemble_kernel(
    const float* __restrict__ pe, const float* __restrict__ row_emb,
    const float* __restrict__ col_emb, const float* __restrict__ cls,
    float* __restrict__ x)
{
    int idx = blockIdx.x * 256 + threadIdx.x;            // over 2704*768
    if (idx >= cN * cE) return;
    int row = idx / cE, e = idx - row * cE;
    int b = row / cSEQ, s = row - b * cSEQ;
    float v;
    if (s == 0) {
        v = cls[e];
    } else {
        int p = s - 1, ph = p / cPW, pw = p - ph * cPW;
        float pos = (e < 384) ? row_emb[ph * 384 + e] : col_emb[pw * 384 + e - 384];
        v = pe[((size_t)b * cNPAT + p) * cE + e] + pos;
    }
    x[idx] = v;
}

// ---------------- fp32 -> bf16 convert (x4 vectorized) ----------------
__global__ __launch_bounds__(256) void f2b_kernel(
    const float* __restrict__ in, bf16* __restrict__ out, int n4)
{
    int i = blockIdx.x * 256 + threadIdx.x;
    if (i >= n4) return;
    f32x4 v = ((const f32x4*)in)[i];
    bf16x4 r;
    r[0] = (bf16)v[0]; r[1] = (bf16)v[1]; r[2] = (bf16)v[2]; r[3] = (bf16)v[3];
    ((bf16x4*)out)[i] = r;
}

// ---------------- batched layer-weight conversion: 4 segments -> wbuf ----------------
// seg sizes (f32x4 units): in_w 442368, out_w 147456, mlp_w1 589824, mlp_w2 589824
__global__ __launch_bounds__(256) void conv4_kernel(
    const float* __restrict__ s0, const float* __restrict__ s1,
    const float* __restrict__ s2, const float* __restrict__ s3,
    bf16* __restrict__ dst)
{
    int i = blockIdx.x * 256 + threadIdx.x;
    if (i >= 1769472) return;
    const float* src; size_t off;
    if (i < 442368)       { src = s0 + (size_t)i * 4;             off = (size_t)i * 4; }
    else if (i < 589824)  { int j = i - 442368;  src = s1 + (size_t)j * 4; off = 1769472 + (size_t)j * 4; }
    else if (i < 1179648) { int j = i - 589824;  src = s2 + (size_t)j * 4; off = 2359296 + (size_t)j * 4; }
    else                  { int j = i - 1179648; src = s3 + (size_t)j * 4; off = 4718592 + (size_t)j * 4; }
    f32x4 v = *(const f32x4*)src;
    bf16x4 r;
    r[0] = (bf16)v[0]; r[1] = (bf16)v[1]; r[2] = (bf16)v[2]; r[3] = (bf16)v[3];
    *(bf16x4*)(dst + off) = r;
}

// ---------------- layernorm over D cols; out bf16 or fp32 ----------------
__global__ __launch_bounds__(256) void ln_kernel(
    const float* __restrict__ x, const float* __restrict__ g,
    const float* __restrict__ bta, bf16* __restrict__ outB,
    float* __restrict__ outF, int D)
{
    const int row = blockIdx.x;
    const float* xr = x + (size_t)row * D;
    float s = 0.f, s2 = 0.f;
    for (int d = threadIdx.x; d < D; d += 256) { float v = xr[d]; s += v; s2 += v * v; }
    #pragma unroll
    for (int off = 32; off > 0; off >>= 1) {
        s  += __shfl_down(s, off);
        s2 += __shfl_down(s2, off);
    }
    __shared__ float rs[4], rs2[4];
    if ((threadIdx.x & 63) == 0) { rs[threadIdx.x >> 6] = s; rs2[threadIdx.x >> 6] = s2; }
    __syncthreads();
    s = rs[0] + rs[1] + rs[2] + rs[3];
    s2 = rs2[0] + rs2[1] + rs2[2] + rs2[3];
    const float mean = s / D;
    const float rstd = rsqrtf(s2 / D - mean * mean + 1e-5f);
    for (int d = threadIdx.x; d < D; d += 256) {
        float v = (xr[d] - mean) * rstd * g[d] + bta[d];
        if (outB) outB[(size_t)row * D + d] = (bf16)v;
        else      outF[(size_t)row * D + d] = v;
    }
}

// ---------------- bf16 MFMA GEMM, 64x64 tile: out = epi(A[M,K] @ W[N,K]^T + bias) ----
// Rationale (round 3): every transformer GEMM here has small K (12-48 k-steps) and a
// grid of only 132-528 blocks at 128-wide tiles -> 1-2 blocks/CU, so the per-k-step
// vmcnt(0) drain (~500 cy uncovered DMA latency) has nothing to hide behind
// (MfmaUtil 5%). 64x64 tiles quadruple the grid (528-2112 blocks) and cut LDS to
// 32 KB -> 5 blocks/CU = up to 20 waves/CU at staggered phases filling each other's
// stalls. Same verified building blocks as the 128^2 kernel: XOR-swizzled LDS rows,
// global_load_lds width=16, identical fragment and C/D layouts.
// Wave w owns a 32x32 quadrant (2x2 fp32x4 accs); stages A/B rows [w*16, w*16+16).
__global__ __launch_bounds__(256, 5) void gemm_sq64_kernel(
    const bf16* __restrict__ A, const bf16* __restrict__ Bw,
    const float* __restrict__ bias, const float* __restrict__ res,
    float* __restrict__ outF, bf16* __restrict__ outB,
    int M, int N, int K, int epi)
{
    __shared__ bf16 sA[2 * 64 * 64];     // 16 KB
    __shared__ bf16 sB[2 * 64 * 64];     // 16 KB

    const int tid  = threadIdx.x;
    const int lane = tid & 63;
    const int wave = tid >> 6;

    const int nwg  = gridDim.x * gridDim.y;
    const int swz  = xcd_swz(blockIdx.y * gridDim.x + blockIdx.x, nwg);
    const int bm = (swz / gridDim.x) * 64;
    const int bn = (swz % gridDim.x) * 64;
    const int wm = (wave & 1) * 32;      // 2x2 wave grid, wave tile 32x32
    const int wn = (wave >> 1) * 32;

    // staging: wave covers rows [wave*16, wave*16+16), 2 DMAs of 8 rows each.
    // lane l -> local row l>>3, global 16B-chunk (l&7)^(l>>3)  (row&7 == l>>3)
    const int r_in = lane >> 3;                    // 0..7
    const int swz_col = ((lane & 7) ^ r_in) * 8;   // global elem offset of this lane's chunk

    const int m_lo = lane & 15;
    const int quad = lane >> 4;

    f32x4 acc[2][2];
    #pragma unroll
    for (int i = 0; i < 2; ++i)
        #pragma unroll
        for (int j = 0; j < 2; ++j) {
            f32x4 z = {0.f, 0.f, 0.f, 0.f};
            acc[i][j] = z;
        }

    const int nk = K >> 6;

    auto stage = [&](int kt, int buf) {
        const int k0 = kt << 6;
        const bf16* gA = A  + (size_t)(bm + wave * 16 + r_in) * K + k0 + swz_col;
        const bf16* gB = Bw + (size_t)(bn + wave * 16 + r_in) * K + k0 + swz_col;
        bf16* lA = sA + buf * 4096 + (wave * 16) * 64;
        bf16* lB = sB + buf * 4096 + (wave * 16) * 64;
        #pragma unroll
        for (int d = 0; d < 2; ++d) {
            async16(gA + (size_t)(d * 8) * K, lA + d * 512);
            async16(gB + (size_t)(d * 8) * K, lB + d * 512);
        }
    };

    stage(0, 0);

    for (int kt = 0; kt < nk; ++kt) {
        __syncthreads();                 // drains vmcnt(0): tile kt landed; all waves done with other buf
        if (kt + 1 < nk) stage(kt + 1, (kt + 1) & 1);

        const bf16* bufA = sA + (kt & 1) * 4096;
        const bf16* bufB = sB + (kt & 1) * 4096;

        bf16x8 af[2][2], bfr[2][2];
        #pragma unroll
        for (int j = 0; j < 2; ++j)
            #pragma unroll
            for (int i = 0; i < 2; ++i) {
                const int c = ((quad + j * 4) ^ (m_lo & 7)) * 8;   // swizzled chunk
                af[j][i]  = *(const bf16x8*)(bufA + (wm + i * 16 + m_lo) * 64 + c);
                bfr[j][i] = *(const bf16x8*)(bufB + (wn + i * 16 + m_lo) * 64 + c);
            }
        #pragma unroll
        for (int j = 0; j < 2; ++j)
            #pragma unroll
            for (int mi = 0; mi < 2; ++mi)
                #pragma unroll
                for (int ni = 0; ni < 2; ++ni)
                    acc[mi][ni] = __builtin_amdgcn_mfma_f32_16x16x32_bf16(
                        af[j][mi], bfr[j][ni], acc[mi][ni], 0, 0, 0);
    }

    // epilogue: C/D layout col=lane&15, row=quad*4+r  (verified m89/m91)
    #pragma unroll
    for (int mi = 0; mi < 2; ++mi) {
        #pragma unroll
        for (int ni = 0; ni < 2; ++ni) {
            #pragma unroll
            for (int r = 0; r < 4; ++r) {
                int row = bm + wm + mi * 16 + quad * 4 + r;
                int col = bn + wn + ni * 16 + m_lo;
                float v = acc[mi][ni][r] + bias[col];
                if (epi == EPI_RES) {
                    v += res[(size_t)row * N + col];
                    outF[(size_t)row * N + col] = v;
                } else if (epi == EPI_GELU_BF16) {
                    v = v * 0.5f * (1.0f + erff(v * 0.70710678118f));
                    outB[(size_t)row * N + col] = (bf16)v;
                } else if (epi == EPI_BF16) {
                    outB[(size_t)row * N + col] = (bf16)v;
                } else {
                    outF[(size_t)row * N + col] = v;
                }
            }
        }
    }
}

// ---------------- MFMA attention: block per (head, image, key-half) ----------------
// 6 waves x 64; wave owns 32 q-rows (169 padded to 192). Block covers 96 keys.
// S = Q K^T via mfma 16x16x32 (Q frags from global, K staged xor-swizzled in LDS).
// Masked softmax with per-row shuffle reduce; P -> bf16 -> per-wave LDS tile.
// O = P V with V^T staged in LDS. Stores UNNORMALIZED partial O + (m,l) per row;
// attn_merge_kernel (NJT=2) combines the two key-halves.
__global__ __launch_bounds__(384) void attn_mfma_kernel(
    const bf16* __restrict__ qkv, bf16* __restrict__ op, float* __restrict__ ml)
{
    __shared__ bf16 sK[KT * cDH];          // 12 KB, xor-swizzled rows
    __shared__ bf16 sVT[cDH * 104];        // 13 KB, V^T, padded stride 104 (2-way banks = free)
    __shared__ bf16 sP[6 * 32 * 104];      // 39 KB, per-wave P tiles
    // total 64 KB exactly -> 2 blocks/CU, all 384 blocks co-resident

    const int h = blockIdx.x, b = blockIdx.y, kt = blockIdx.z;
    const int tid  = threadIdx.x;
    const int lane = tid & 63, wave = tid >> 6;
    const int m_lo = lane & 15, quad = lane >> 4;
    const int K0 = kt * KT;
    const int rowb = b * cSEQ;

    // ---- stage K rows K0..K0+95 (clamped; padded keys masked later), async ----
    {
        const int r_in = lane >> 3;
        const int swz = ((lane & 7) ^ r_in) * 8;
        #pragma unroll
        for (int d = 0; d < 2; ++d) {
            int key = K0 + wave * 16 + d * 8 + r_in;
            int grow = rowb + min(key, cSEQ - 1);
            async16(qkv + (size_t)grow * (3 * cE) + cE + h * cDH + swz,
                    sK + (wave * 16 + d * 8) * cDH);
        }
    }
    // ---- stage V^T (d-major): coalesced u32 global reads, scalar LDS writes ----
    for (int idx = tid; idx < KT * 32; idx += 384) {
        int key = idx >> 5, dp = idx & 31;
        int grow = rowb + min(K0 + key, cSEQ - 1);
        unsigned v = *(const unsigned*)(qkv + (size_t)grow * (3 * cE) + 2 * cE + h * cDH + dp * 2);
        sVT[(dp * 2) * 104 + key]     = ((const bf16*)&v)[0];
        sVT[(dp * 2 + 1) * 104 + key] = ((const bf16*)&v)[1];
    }
    // ---- Q fragments straight from global (row-clamped for q-padding) ----
    bf16x8 qf[2][2];
    #pragma unroll
    for (int j = 0; j < 2; ++j)
        #pragma unroll
        for (int s = 0; s < 2; ++s) {
            int qrow = min(wave * 32 + j * 16 + m_lo, cSEQ - 1);
            qf[j][s] = *(const bf16x8*)(qkv + (size_t)(rowb + qrow) * (3 * cE)
                                        + h * cDH + s * 32 + quad * 8);
        }
    __syncthreads();   // drains async K DMAs (vmcnt 0) + VT writes

    // ---- S = Q K^T : 2 q-subtiles x 6 key-tiles, K-dim 64 = 2 mfma steps ----
    f32x4 sc[2][6];
    #pragma unroll
    for (int j = 0; j < 2; ++j)
        #pragma unroll
        for (int t = 0; t < 6; ++t) {
            f32x4 z = {0.f, 0.f, 0.f, 0.f};
            sc[j][t] = z;
        }
    #pragma unroll
    for (int t = 0; t < 6; ++t)
        #pragma unroll
        for (int s2 = 0; s2 < 2; ++s2) {
            const int c = ((quad + s2 * 4) ^ (m_lo & 7)) * 8;
            bf16x8 kf = *(const bf16x8*)(sK + (t * 16 + m_lo) * cDH + c);
            #pragma unroll
            for (int j = 0; j < 2; ++j)
                sc[j][t] = __builtin_amdgcn_mfma_f32_16x16x32_bf16(qf[j][s2], kf, sc[j][t], 0, 0, 0);
        }

    // ---- masked softmax; rows q = 16j+quad*4+r, cols key = 16t+m_lo ----
    bf16* sPw = sP + wave * (32 * 104);
    #pragma unroll
    for (int j = 0; j < 2; ++j) {
        float mr[4] = {-1e30f, -1e30f, -1e30f, -1e30f};
        #pragma unroll
        for (int t = 0; t < 6; ++t) {
            const bool pad = (K0 + t * 16 + m_lo) >= cSEQ;
            #pragma unroll
            for (int r = 0; r < 4; ++r) {
                float v = sc[j][t][r] * 0.125f;       // 1/sqrt(64)
                if (pad) v = -1e30f;
                sc[j][t][r] = v;
                mr[r] = fmaxf(mr[r], v);
            }
        }
        #pragma unroll
        for (int r = 0; r < 4; ++r) {
            mr[r] = fmaxf(mr[r], __shfl_xor(mr[r], 1));
            mr[r] = fmaxf(mr[r], __shfl_xor(mr[r], 2));
            mr[r] = fmaxf(mr[r], __shfl_xor(mr[r], 4));
            mr[r] = fmaxf(mr[r], __shfl_xor(mr[r], 8));
        }
        float lr[4] = {0.f, 0.f, 0.f, 0.f};
        #pragma unroll
        for (int t = 0; t < 6; ++t)
            #pragma unroll
            for (int r = 0; r < 4; ++r) {
                float p = __expf(sc[j][t][r] - mr[r]);
                lr[r] += p;
                sPw[(j * 16 + quad * 4 + r) * 104 + t * 16 + m_lo] = (bf16)p;
            }
        #pragma unroll
        for (int r = 0; r < 4; ++r) {
            lr[r] += __shfl_xor(lr[r], 1);
            lr[r] += __shfl_xor(lr[r], 2);
            lr[r] += __shfl_xor(lr[r], 4);
            lr[r] += __shfl_xor(lr[r], 8);
        }
        if (m_lo == 0) {
            #pragma unroll
            for (int r = 0; r < 4; ++r) {
                int qg = wave * 32 + j * 16 + quad * 4 + r;
                if (qg < cSEQ) {
                    int pi = ((b * cHEADS + h) * NJT + kt) * cSEQ + qg;
                    ml[pi * 2]     = mr[r];
                    ml[pi * 2 + 1] = lr[r];
                }
            }
        }
    }

    // ---- O = P V : 96 keys = exactly 3 mfma k-steps (no pad reads) ----
    f32x4 oc[2][4];
    #pragma unroll
    for (int j = 0; j < 2; ++j)
        #pragma unroll
        for (int dt = 0; dt < 4; ++dt) {
            f32x4 z = {0.f, 0.f, 0.f, 0.f};
            oc[j][dt] = z;
        }
    #pragma unroll
    for (int s3 = 0; s3 < 3; ++s3) {
        bf16x8 pa[2], vf[4];
        #pragma unroll
        for (int j = 0; j < 2; ++j)
            pa[j] = *(const bf16x8*)(sPw + (j * 16 + m_lo) * 104 + s3 * 32 + quad * 8);
        #pragma unroll
        for (int dt = 0; dt < 4; ++dt)
            vf[dt] = *(const bf16x8*)(sVT + (dt * 16 + m_lo) * 104 + s3 * 32 + quad * 8);
        #pragma unroll
        for (int j = 0; j < 2; ++j)
            #pragma unroll
            for (int dt = 0; dt < 4; ++dt)
                oc[j][dt] = __builtin_amdgcn_mfma_f32_16x16x32_bf16(pa[j], vf[dt], oc[j][dt], 0, 0, 0);
    }

    // ---- store unnormalized partial O (merge kernel normalizes) ----
    #pragma unroll
    for (int j = 0; j < 2; ++j)
        #pragma unroll
        for (int dt = 0; dt < 4; ++dt)
            #pragma unroll
            for (int r = 0; r < 4; ++r) {
                int qg = wave * 32 + j * 16 + quad * 4 + r;
                if (qg < cSEQ) {
                    int pi = ((b * cHEADS + h) * NJT + kt) * cSEQ + qg;
                    op[(size_t)pi * cDH + dt * 16 + m_lo] = (bf16)oc[j][dt][r];
                }
            }
}

// ---------------- attention part 2: merge 2 key-half partials ----------------
__global__ __launch_bounds__(256) void attn_merge_kernel(
    const bf16* __restrict__ op, const float* __restrict__ ml,
    bf16* __restrict__ attn_o)
{
    int idx = blockIdx.x * 256 + threadIdx.x;   // over 192*169*8
    if (idx >= cB * cHEADS * cSEQ * 8) return;
    int d8 = idx & 7;
    int t  = idx >> 3;
    int q  = t % cSEQ;
    int bh = t / cSEQ;
    int b = bh / cHEADS, h = bh - b * cHEADS;
    const int pbase = (bh * NJT) * cSEQ + q;    // + jt*cSEQ per tile

    float ms[NJT], ls[NJT], mstar = -1e30f;
    #pragma unroll
    for (int j = 0; j < NJT; ++j) {
        ms[j] = ml[(pbase + j * cSEQ) * 2];
        ls[j] = ml[(pbase + j * cSEQ) * 2 + 1];
        mstar = fmaxf(mstar, ms[j]);
    }
    float den = 0.f, acc[8];
    #pragma unroll
    for (int u = 0; u < 8; ++u) acc[u] = 0.f;
    #pragma unroll
    for (int j = 0; j < NJT; ++j) {
        float w = __expf(ms[j] - mstar);
        den += w * ls[j];
        bf16x8 v = *(const bf16x8*)(op + (size_t)(pbase + j * cSEQ) * cDH + d8 * 8);
        #pragma unroll
        for (int u = 0; u < 8; ++u) acc[u] += w * (float)v[u];
    }
    float inv = 1.0f / den;
    bf16* outp = attn_o + ((size_t)(b * cSEQ + q)) * cE + h * cDH + d8 * 8;
    #pragma unroll
    for (int u = 0; u < 8; ++u) outp[u] = (bf16)(acc[u] * inv);
}

// ---------------- vis_mask: 2704 ones (read back as float32) ----------------
__global__ __launch_bounds__(256) void mask_kernel(float* __restrict__ out)
{
    int i = blockIdx.x * 256 + threadIdx.x;
    if (i < cN) out[i] = 1.0f;
}

// ---------------- host orchestration ----------------
extern "C" void kernel_launch(void* const* d_in, const int* in_sizes, int n_in,
                              void* d_out, int out_size, void* d_ws, size_t ws_size,
                              hipStream_t stream)
{
    const float* pixel   = (const float*)d_in[0];
    const float* patch_W = (const float*)d_in[1];
    const float* patch_b = (const float*)d_in[2];
    const float* row_emb = (const float*)d_in[3];
    const float* col_emb = (const float*)d_in[4];
    const float* cls     = (const float*)d_in[5];
    const float* ln1_g   = (const float*)d_in[6];
    const float* ln1_b   = (const float*)d_in[7];
    const float* in_w    = (const float*)d_in[8];
    const float* in_b    = (const float*)d_in[9];
    const float* out_w   = (const float*)d_in[10];
    const float* out_b   = (const float*)d_in[11];
    const float* ln2_g   = (const float*)d_in[12];
    const float* ln2_b   = (const float*)d_in[13];
    const float* mlp_w1  = (const float*)d_in[14];
    const float* mlp_b1  = (const float*)d_in[15];
    const float* mlp_w2  = (const float*)d_in[16];
    const float* mlp_b2  = (const float*)d_in[17];
    const float* fin_g   = (const float*)d_in[18];
    const float* fin_b   = (const float*)d_in[19];
    const float* br_w1   = (const float*)d_in[20];
    const float* br_b1   = (const float*)d_in[21];
    const float* br_w2   = (const float*)d_in[22];
    const float* br_b2   = (const float*)d_in[23];
    const float* br_g    = (const float*)d_in[24];
    const float* br_b    = (const float*)d_in[25];

    // workspace layout; top = 70,385,664 B
    char* ws = (char*)d_ws;
    float* x      = (float*)(ws);                        // [2816,768] f32,  8,650,752
    bf16*  xn     = (bf16 *)(ws + 8650752);              // [2816,768] bf16, 4,325,376
    bf16*  qkv    = (bf16 *)(ws + 12976128);             // [2816,2304] bf16, 12,976,128
    bf16*  attn_o = (bf16 *)(ws + 25952256);             // [2816,768] bf16, 4,325,376
    bf16*  hmlp   = (bf16 *)(ws + 30277632);             // [2816,3072] bf16, 17,301,504
    bf16*  hb1    = (bf16 *)(ws + 47579136);             // [2816,1536] bf16, 8,650,752
    bf16*  wbuf   = (bf16 *)(ws + 56229888);             // 7,077,888 elems = 14,155,776 B
    // aliases (disjoint lifetimes):
    float* pe     = (float*)(ws + 30277632);             // [2688,768] f32 (patch phase)
    bf16*  Apatch = (bf16 *)(ws + 47579136);             // [2688,768] bf16 (patch phase)
    bf16*  att_op = (bf16 *)(ws + 30277632);             // 8.3 MB used (attn phase, pre-MLP1)
    float* att_ml = (float*)(ws + 47579136);             // 519 KB used (attn phase, pre-branch)
    float* h2     = (float*)(ws + 12976128);             // [2816,2048] f32 (branch phase)

    auto conv = [&](const float* src, bf16* dst, int n) {
        int n4 = n / 4;
        f2b_kernel<<<(n4 + 255) / 256, 256, 0, stream>>>(src, dst, n4);
    };
    auto gemm = [&](const bf16* Abf, const bf16* Wbf, const float* bias,
                    const float* resid, float* oF, bf16* oB,
                    int M, int N, int K, int epi) {
        dim3 g(N / 64, M / 64);
        gemm_sq64_kernel<<<g, 256, 0, stream>>>(Abf, Wbf, bias, resid, oF, oB, M, N, K, epi);
    };

    // ---- patch embed ----
    patchify_kernel<<<(cB * cNPAT * cE + 255) / 256, 256, 0, stream>>>(pixel, Apatch);
    conv(patch_W, wbuf, cE * cE);
    gemm(Apatch, wbuf, patch_b, nullptr, pe, nullptr, cB * cNPAT, cE, cE, EPI_F32);
    assemble_kernel<<<(cN * cE + 255) / 256, 256, 0, stream>>>(pe, row_emb, col_emb, cls, x);

    const int merge_n = cB * cHEADS * cSEQ * 8;
    // wbuf per-layer offsets
    bf16* w_qkv = wbuf;
    bf16* w_out = wbuf + 1769472;
    bf16* w_m1  = wbuf + 2359296;
    bf16* w_m2  = wbuf + 4718592;

    // ---- transformer layers ----
    for (int l = 0; l < cL; ++l) {
        conv4_kernel<<<(1769472 + 255) / 256, 256, 0, stream>>>(
            in_w  + (size_t)l * 3 * cE * cE,
            out_w + (size_t)l * cE * cE,
            mlp_w1 + (size_t)l * cMLP * cE,
            mlp_w2 + (size_t)l * cE * cMLP, wbuf);
        ln_kernel<<<cN, 256, 0, stream>>>(x, ln1_g + l * cE, ln1_b + l * cE, xn, nullptr, cE);
        gemm(xn, w_qkv, in_b + (size_t)l * 3 * cE, nullptr, nullptr, qkv, cMp, 3 * cE, cE, EPI_BF16);
        attn_mfma_kernel<<<dim3(cHEADS, cB, NJT), 384, 0, stream>>>(qkv, att_op, att_ml);
        attn_merge_kernel<<<(merge_n + 255) / 256, 256, 0, stream>>>(att_op, att_ml, attn_o);
        gemm(attn_o, w_out, out_b + (size_t)l * cE, x, x, nullptr, cMp, cE, cE, EPI_RES);
        ln_kernel<<<cN, 256, 0, stream>>>(x, ln2_g + l * cE, ln2_b + l * cE, xn, nullptr, cE);
        gemm(xn, w_m1, mlp_b1 + (size_t)l * cMLP, nullptr, nullptr, hmlp, cMp, cMLP, cE, EPI_GELU_BF16);
        gemm(hmlp, w_m2, mlp_b2 + (size_t)l * cE, x, x, nullptr, cMp, cE, cMLP, EPI_RES);
    }

    // ---- final LN + branch head ----
    ln_kernel<<<cN, 256, 0, stream>>>(x, fin_g, fin_b, xn, nullptr, cE);
    conv(br_w1, wbuf, 2 * cE * cE);
    conv(br_w2, wbuf + 1179648, cOUT * 2 * cE);
    gemm(xn, wbuf, br_b1, nullptr, nullptr, hb1, cMp, 2 * cE, cE, EPI_GELU_BF16);
    gemm(hb1, wbuf + 1179648, br_b2, nullptr, h2, nullptr, cMp, cOUT, 2 * cE, EPI_F32);
    ln_kernel<<<cN, 256, 0, stream>>>(h2, br_g, br_b, nullptr, (float*)d_out, cOUT);

    // ---- vis_mask ----
    mask_kernel<<<(cN + 255) / 256, 256, 0, stream>>>((float*)d_out + (size_t)cN * cOUT);
}